// Round 21
// baseline (269.140 us; speedup 1.0000x reference)
//
#include <hip/hip_runtime.h>

typedef _Float16 f16;
typedef __attribute__((ext_vector_type(2))) __fp16 fp16x2_raw;
typedef __attribute__((ext_vector_type(4))) _Float16 f16x4;
typedef __attribute__((ext_vector_type(8))) _Float16 f16x8;
typedef __attribute__((ext_vector_type(4))) float f32x4;
typedef __attribute__((ext_vector_type(16))) float f32x16;
typedef __attribute__((ext_vector_type(2))) unsigned int u32x2;
typedef __attribute__((ext_vector_type(4))) unsigned int u32x4;

#define NB 4
#define NS 2048
#define NE 1024
#define NH 16
#define ND 64
#define NM (NB*NS)   // 8192 tokens
#define NROW (NB*NS*NH)   // 131072 (token,head) rows... actually 64 bh x 2048 q = 131072

__device__ __forceinline__ void gld16(const void* g, void* l) {
  __builtin_amdgcn_global_load_lds((const __attribute__((address_space(1))) unsigned int*)g,
                                   (__attribute__((address_space(3))) unsigned int*)l, 16, 0, 0);
}

// pack two f32 -> one u32 of 2 f16 (v_cvt_pkrtz_f16_f32)
__device__ __forceinline__ unsigned cvt2h(float a, float b) {
  fp16x2_raw r = __builtin_amdgcn_cvt_pkrtz(a, b);
  return __builtin_bit_cast(unsigned, r);
}

// proven (R5==R6, distinct-value operands so no reg-coalesce hazard):
// new_a[l] = l<32 ? a[l] : b[l-32]; new_b[l] = l<32 ? a[l+32] : b[l]
__device__ __forceinline__ void plswap(unsigned& a, unsigned& b) {
  asm volatile("v_permlane32_swap_b32 %0, %1" : "+v"(a), "+v"(b));
}
// NOTE: a==b plswap variant miscompiles (R9/R10). Cross-half reductions use __shfl_xor(x,32).

// ---------------- f32 -> f16 convert, WEIGHTS ONLY ----------------
__global__ __launch_bounds__(256) void cvt_w(const float* __restrict__ s3, const float* __restrict__ s4,
                                             const float* __restrict__ s5, const float* __restrict__ s6,
                                             f16* __restrict__ dst) {
  const int W = NE*NE/4;
  const int total = 4*W;
  int idx = blockIdx.x * blockDim.x + threadIdx.x;
  int stride = gridDim.x * blockDim.x;
  for (int i = idx; i < total; i += stride) {
    const float* src; int off;
    if      (i <   W)   { src = s3; off = i; }
    else if (i < 2*W)   { src = s4; off = i - W; }
    else if (i < 3*W)   { src = s5; off = i - 2*W; }
    else                { src = s6; off = i - 3*W; }
    float4 v = ((const float4*)src)[off];
    f16x4 o;
    o[0] = (_Float16)v.x; o[1] = (_Float16)v.y; o[2] = (_Float16)v.z; o[3] = (_Float16)v.w;
    ((f16x4*)dst)[i] = o;
  }
}

// ---------------- NT GEMM (R20-proven): dbuf + explicit drain + XCD swizzle; AF32 fused convert ----------------
template<bool AF32, bool OUTF32>
__global__ __launch_bounds__(256)
void gemm_bt(const void* __restrict__ Asrc, const f16* __restrict__ Bw,
             const float* __restrict__ bias, float* __restrict__ Cf,
             f16* __restrict__ Ch, int M, int N, int K)
{
  __shared__ __align__(16) f16 As[2*128*32];
  __shared__ __align__(16) f16 Bs[2*128*32];
  const int t = threadIdx.x;
  const int l = t & 63, w = t >> 6;
  const int wr = w >> 1, wc = w & 1;

  const int id = blockIdx.x + blockIdx.y * gridDim.x;
  const int xcd = id & 7, slot = id >> 3;
  const int m0 = (((slot >> 3) << 3) | xcd) * 128;
  const int n0 = (slot & 7) * 128;

  f32x4 acc[4][4];
  #pragma unroll
  for (int i = 0; i < 4; ++i)
    #pragma unroll
    for (int j = 0; j < 4; ++j)
      acc[i][j] = f32x4{0.f, 0.f, 0.f, 0.f};

  const int off0 = (w*2+0)*1024 + l*16;
  const int off1 = (w*2+1)*1024 + l*16;
  const int row0 = off0 >> 6, k0 = (off0 & 63) >> 1;
  const int row1 = off1 >> 6, k1 = (off1 & 63) >> 1;
  const f16*   a0h = (const f16*)Asrc   + (size_t)(m0+row0)*K + k0;
  const f16*   a1h = (const f16*)Asrc   + (size_t)(m0+row1)*K + k1;
  const float* a0f = (const float*)Asrc + (size_t)(m0+row0)*K + k0;
  const float* a1f = (const float*)Asrc + (size_t)(m0+row1)*K + k1;
  const f16* b0 = Bw + (size_t)(n0+row0)*K + k0;
  const f16* b1 = Bw + (size_t)(n0+row1)*K + k1;

  const int aoff = (wr*64 + (l&15))*32 + ((l>>4)<<3);
  const int boff = (wc*64 + (l&15))*32 + ((l>>4)<<3);

  gld16(b0, Bs + off0/2);
  gld16(b1, Bs + off1/2);
  if constexpr (AF32) {
    float4 x0 = *(const float4*)(a0f);
    float4 x1 = *(const float4*)(a0f + 4);
    float4 y0 = *(const float4*)(a1f);
    float4 y1 = *(const float4*)(a1f + 4);
    u32x4 wa, wb;
    wa[0] = cvt2h(x0.x, x0.y); wa[1] = cvt2h(x0.z, x0.w);
    wa[2] = cvt2h(x1.x, x1.y); wa[3] = cvt2h(x1.z, x1.w);
    wb[0] = cvt2h(y0.x, y0.y); wb[1] = cvt2h(y0.z, y0.w);
    wb[2] = cvt2h(y1.x, y1.y); wb[3] = cvt2h(y1.z, y1.w);
    *(u32x4*)(As + off0/2) = wa;
    *(u32x4*)(As + off1/2) = wb;
  } else {
    gld16(a0h, As + off0/2);
    gld16(a1h, As + off1/2);
  }
  asm volatile("s_waitcnt vmcnt(0)" ::: "memory");
  __syncthreads();

  const int NK = K / 32;
  for (int ksi = 0; ksi < NK; ++ksi) {
    const int cur = ksi & 1, nxt = cur ^ 1;
    float4 x0, x1, y0, y1;
    if (ksi < NK-1) {
      const int kt = (ksi+1) * 32;
      gld16(b0 + kt, Bs + nxt*4096 + off0/2);
      gld16(b1 + kt, Bs + nxt*4096 + off1/2);
      if constexpr (AF32) {
        x0 = *(const float4*)(a0f + kt);
        x1 = *(const float4*)(a0f + kt + 4);
        y0 = *(const float4*)(a1f + kt);
        y1 = *(const float4*)(a1f + kt + 4);
      } else {
        gld16(a0h + kt, As + nxt*4096 + off0/2);
        gld16(a1h + kt, As + nxt*4096 + off1/2);
      }
    }
    const f16* Ac = As + cur*4096;
    const f16* Bc = Bs + cur*4096;
    f16x8 af[4], bf[4];
    #pragma unroll
    for (int i = 0; i < 4; ++i) af[i] = *(const f16x8*)(Ac + aoff + i*512);
    #pragma unroll
    for (int j = 0; j < 4; ++j) bf[j] = *(const f16x8*)(Bc + boff + j*512);
    #pragma unroll
    for (int i = 0; i < 4; ++i)
      #pragma unroll
      for (int j = 0; j < 4; ++j)
        acc[i][j] = __builtin_amdgcn_mfma_f32_16x16x32_f16(af[i], bf[j], acc[i][j], 0, 0, 0);
    asm volatile("s_waitcnt vmcnt(0)" ::: "memory");
    if constexpr (AF32) {
      if (ksi < NK-1) {
        u32x4 wa, wb;
        wa[0] = cvt2h(x0.x, x0.y); wa[1] = cvt2h(x0.z, x0.w);
        wa[2] = cvt2h(x1.x, x1.y); wa[3] = cvt2h(x1.z, x1.w);
        wb[0] = cvt2h(y0.x, y0.y); wb[1] = cvt2h(y0.z, y0.w);
        wb[2] = cvt2h(y1.x, y1.y); wb[3] = cvt2h(y1.z, y1.w);
        *(u32x4*)(As + nxt*4096 + off0/2) = wa;
        *(u32x4*)(As + nxt*4096 + off1/2) = wb;
      }
    }
    __syncthreads();
  }

  #pragma unroll
  for (int j = 0; j < 4; ++j) {
    const int col = n0 + wc*64 + j*16 + (l & 15);
    const float bb = bias[col];
    #pragma unroll
    for (int i = 0; i < 4; ++i) {
      const int rowb = m0 + wr*64 + i*16 + ((l>>4)<<2);
      #pragma unroll
      for (int r = 0; r < 4; ++r) {
        float v = acc[i][j][r] + bb;
        if constexpr (OUTF32) Cf[(size_t)(rowb+r)*N + col] = v;
        else                  Ch[(size_t)(rowb+r)*N + col] = (f16)v;
      }
    }
  }
}

// ---------------- flash attention: split-key across blocks (z = key half) ----------------
// grid (16,64,2), 256 thr = 4 waves. Each block: 1024 keys, 16 iters, single-buffer 16KB
// (R11-proven shell, R15-proven arithmetic). Epilogue stores NORMALIZED partial o/l (f16)
// + (m,l) f32 per q-row; attn_combine merges the two halves.
__global__ __launch_bounds__(256, 4)
void attn_kernel(const f16* __restrict__ Q, const f16* __restrict__ K,
                 const f16* __restrict__ V, f16* __restrict__ Opart, float2* __restrict__ ml)
{
  __shared__ __align__(16) f16 S_lds[8192];   // [0,4096): K tile, [4096,8192): Vt tile

  const int t = threadIdx.x, l = t & 63, w = t >> 6;
  const int lq = l & 31, hi = l >> 5;

  const int lin = blockIdx.x + (blockIdx.y << 4);
  const int xcd = lin & 7, jj = lin >> 3;
  const int bh = xcd * 8 + (jj >> 4);
  const int qt = jj & 15;
  const int bz = blockIdx.z;           // key half: 0 or 1
  const int b = bh >> 4, h = bh & 15;
  const size_t base = (size_t)b * NS * NE + (size_t)h * ND;
  const int qrow = qt*128 + w*32 + lq;
  const int koff = bz * (NS/2);

  // Q B-fragments
  f16x8 bq[4];
  #pragma unroll
  for (int ks = 0; ks < 4; ++ks)
    bq[ks] = *(const f16x8*)&Q[base + (size_t)qrow*NE + ks*16 + hi*8];
  asm volatile("s_waitcnt vmcnt(0)" ::: "memory");

  f32x16 o[2];
  #pragma unroll
  for (int dt = 0; dt < 2; ++dt)
    #pragma unroll
    for (int r = 0; r < 16; ++r) o[dt][r] = 0.f;
  float m2 = -3e38f, lsum = 0.f;
  const float K2 = 0.125f * 1.44269504089f;

  // ---- K staging src (inverse-permuted; proven) ----
  const int krow0 = w*16 + (l>>3);
  const int kgran = ((l&7) ^ (l>>3)) * 8;
  const f16* kSrc0 = K + base + (size_t)(koff + krow0)*NE + kgran;
  const f16* kSrc1 = kSrc0 + (size_t)8*NE;
  // ---- V staging src: lane = key row l, d-chunk = w*16..+15 (proven) ----
  const f16* vSrc = V + base + (size_t)(koff + l)*NE + w*16;

  f16* kDst0 = &S_lds[0] + (w*2+0)*512 + l*8;
  f16* kDst1 = &S_lds[0] + (w*2+1)*512 + l*8;
  const char* ksb = (const char*)&S_lds[0];
  char* vtb = (char*)&S_lds[4096];

  const size_t tileAdv = (size_t)64 * NE;

  for (int it = 0; it < 16; ++it) {
    const size_t g = (size_t)it * tileAdv;
    __syncthreads();
    gld16(kSrc0 + g, kDst0);
    gld16(kSrc1 + g, kDst1);
    {
      f16x8 va = *(const f16x8*)(vSrc + g);
      f16x8 vb = *(const f16x8*)(vSrc + g + 8);
      #pragma unroll
      for (int i = 0; i < 8; ++i) {
        const int d0 = w*16 + i, d1 = w*16 + 8 + i;   // d&7 == i&7 for both
        *(f16*)(vtb + ((d0*128 + l*2) ^ ((i & 7) << 4))) = va[i];
        *(f16*)(vtb + ((d1*128 + l*2) ^ ((i & 7) << 4))) = vb[i];
      }
    }
    asm volatile("s_waitcnt vmcnt(0)" ::: "memory");   // explicit drain of K DMAs (R19 doctrine)
    __syncthreads();

    // ---- S^T = K * Q^T ----
    f32x16 s[2];
    #pragma unroll
    for (int ct = 0; ct < 2; ++ct)
      #pragma unroll
      for (int r = 0; r < 16; ++r) s[ct][r] = 0.f;
    __builtin_amdgcn_s_setprio(1);
    #pragma unroll
    for (int ct = 0; ct < 2; ++ct) {
      const int krow = ct*32 + lq;
      const int rswz = (krow & 7) << 4;
      #pragma unroll
      for (int ks = 0; ks < 4; ++ks) {
        f16x8 ak = *(const f16x8*)(ksb + ((krow*128 + ks*32 + hi*16) ^ rswz));
        s[ct] = __builtin_amdgcn_mfma_f32_32x32x16_f16(ak, bq[ks], s[ct], 0, 0, 0);
      }
    }
    __builtin_amdgcn_s_setprio(0);

    // ---- pairwise-tree max ----
    float mm[16];
    #pragma unroll
    for (int r = 0; r < 16; ++r) mm[r] = fmaxf(s[0][r], s[1][r]);
    #pragma unroll
    for (int st = 8; st > 0; st >>= 1)
      #pragma unroll
      for (int r = 0; r < st; ++r) mm[r] = fmaxf(mm[r], mm[r+st]);
    float mx = mm[0] * K2;
    mx = fmaxf(mx, __shfl_xor(mx, 32));

    // ---- defer-rescale (THR=8 in log2) ----
    if (__any(mx > m2 + 8.0f)) {
      const float mnew = fmaxf(m2, mx);
      const float alpha = __builtin_amdgcn_exp2f(m2 - mnew);
      m2 = mnew;
      lsum *= alpha;
      #pragma unroll
      for (int dt = 0; dt < 2; ++dt)
        #pragma unroll
        for (int r = 0; r < 16; ++r) o[dt][r] *= alpha;
    }

    // ---- exp + 4-way split psum ----
    float ps4[4] = {0.f, 0.f, 0.f, 0.f};
    #pragma unroll
    for (int ct = 0; ct < 2; ++ct)
      #pragma unroll
      for (int r = 0; r < 16; ++r) {
        float p = __builtin_amdgcn_exp2f(s[ct][r]*K2 - m2);
        s[ct][r] = p;
        ps4[r & 3] += p;
      }
    lsum += (ps4[0] + ps4[1]) + (ps4[2] + ps4[3]);

    // ---- pack P, build PV B-operands via plswap (distinct values: proven) ----
    f16x8 pa[4];
    #pragma unroll
    for (int ct = 0; ct < 2; ++ct) {
      unsigned wd[8];
      #pragma unroll
      for (int m = 0; m < 4; ++m)
        #pragma unroll
        for (int hh = 0; hh < 2; ++hh)
          wd[m*2 + hh] = cvt2h(s[ct][4*m + 2*hh], s[ct][4*m + 2*hh + 1]);
      #pragma unroll
      for (int ks2 = 0; ks2 < 2; ++ks2) {
        unsigned a0 = wd[(2*ks2)*2 + 0], b0 = wd[(2*ks2+1)*2 + 0];
        unsigned a1 = wd[(2*ks2)*2 + 1], b1 = wd[(2*ks2+1)*2 + 1];
        plswap(a0, b0);
        plswap(a1, b1);
        union { unsigned u[4]; f16x8 v; } pp;
        pp.u[0] = a0; pp.u[1] = a1; pp.u[2] = b0; pp.u[3] = b1;
        pa[ct*2 + ks2] = pp.v;
      }
    }

    // ---- O^T += V^T * P ----
    __builtin_amdgcn_s_setprio(1);
    #pragma unroll
    for (int ks = 0; ks < 4; ++ks)
      #pragma unroll
      for (int dt = 0; dt < 2; ++dt) {
        const int drow = dt*32 + lq;
        f16x8 av = *(const f16x8*)(vtb + ((drow*128 + ks*32 + hi*16) ^ ((drow & 7) << 4)));
        o[dt] = __builtin_amdgcn_mfma_f32_32x32x16_f16(av, pa[ks], o[dt], 0, 0, 0);
      }
    __builtin_amdgcn_s_setprio(0);
  }

  // ---- epilogue: normalized partial (o/l) to Opart[bz], (m,l) to ml ----
  const float lt = lsum + __shfl_xor(lsum, 32);
  const float linv = 1.0f / lt;
  f16* Od = Opart + (size_t)bz * ((size_t)NM * NE);
  #pragma unroll
  for (int dt = 0; dt < 2; ++dt)
    #pragma unroll
    for (int m = 0; m < 4; ++m) {
      u32x2 st;
      st.x = cvt2h(o[dt][4*m+0]*linv, o[dt][4*m+1]*linv);
      st.y = cvt2h(o[dt][4*m+2]*linv, o[dt][4*m+3]*linv);
      const int d = dt*32 + 8*m + 4*hi;
      *(u32x2*)&Od[base + (size_t)qrow*NE + d] = st;
    }
  if (hi == 0) {
    const int rid = bh*NS + qrow;
    ml[(size_t)bz*131072 + rid] = float2{m2, lt};
  }
}

// ---------------- combine the two key-half partials ----------------
__global__ __launch_bounds__(256)
void attn_combine(const f16* __restrict__ Opart, const float2* __restrict__ ml,
                  f16* __restrict__ O)
{
  const int gid = blockIdx.x * 256 + threadIdx.x;   // 131072 rows x 8 d-groups
  const int rid = gid >> 3;
  const int dg  = (gid & 7) << 3;
  const int bh = rid >> 11;          // / NS
  const int qrow = rid & (NS - 1);
  const int b = bh >> 4, h = bh & 15;
  const size_t addr = ((size_t)(b*NS + qrow))*NE + h*ND + dg;

  const float2 a = ml[rid];
  const float2 c = ml[131072 + rid];
  const float ms = fmaxf(a.x, c.x);
  const float w0 = __builtin_amdgcn_exp2f(a.x - ms) * a.y;
  const float w1 = __builtin_amdgcn_exp2f(c.x - ms) * c.y;
  const float inv = 1.0f / (w0 + w1);
  const float c0 = w0 * inv, c1 = w1 * inv;

  f16x8 o0 = *(const f16x8*)&Opart[addr];
  f16x8 o1 = *(const f16x8*)&Opart[(size_t)NM*NE + addr];
  u32x4 st;
  #pragma unroll
  for (int i = 0; i < 4; ++i)
    st[i] = cvt2h((float)o0[2*i]*c0 + (float)o1[2*i]*c1,
                  (float)o0[2*i+1]*c0 + (float)o1[2*i+1]*c1);
  *(u32x4*)&O[addr] = st;
}

// ---------------- launch ----------------
extern "C" void kernel_launch(void* const* d_in, const int* in_sizes, int n_in,
                              void* d_out, int out_size, void* d_ws, size_t ws_size,
                              hipStream_t stream)
{
  const float* q_in = (const float*)d_in[0];
  const float* k_in = (const float*)d_in[1];
  const float* v_in = (const float*)d_in[2];
  const float* Wq = (const float*)d_in[3];
  const float* bq = (const float*)d_in[4];
  const float* Wk = (const float*)d_in[5];
  const float* bk = (const float*)d_in[6];
  const float* Wv = (const float*)d_in[7];
  const float* bv = (const float*)d_in[8];
  const float* Wo = (const float*)d_in[9];
  const float* bo = (const float*)d_in[10];

  char* ws = (char*)d_ws;
  f16*    Opart = (f16*)(ws + 0);            // 2 x 16 MB normalized partials
  float2* mlb   = (float2*)(ws + 33554432);  // 2 x 131072 float2 = 2 MB
  f16* Wq16 = (f16*)(ws + 50331648);
  f16* Wk16 = (f16*)(ws + 52428800);
  f16* Wv16 = (f16*)(ws + 54525952);
  f16* Wo16 = (f16*)(ws + 56623104);
  f16* Qp   = (f16*)(ws + 58720256);
  f16* Kp   = (f16*)(ws + 75497472);
  f16* Vp   = (f16*)(ws + 92274688);
  f16* Op   = (f16*)(ws + 109051904);

  cvt_w<<<1024, 256, 0, stream>>>(Wq, Wk, Wv, Wo, Wq16);

  dim3 gg(8, 64);
  gemm_bt<true,  false><<<gg, 256, 0, stream>>>(q_in, Wq16, bq, nullptr, Qp, NM, NE, NE);
  gemm_bt<true,  false><<<gg, 256, 0, stream>>>(k_in, Wk16, bk, nullptr, Kp, NM, NE, NE);
  gemm_bt<true,  false><<<gg, 256, 0, stream>>>(v_in, Wv16, bv, nullptr, Vp, NM, NE, NE);

  attn_kernel<<<dim3(16, 64, 2), 256, 0, stream>>>(Qp, Kp, Vp, Opart, mlb);
  attn_combine<<<4096, 256, 0, stream>>>(Opart, mlb, Op);

  gemm_bt<false, true><<<gg, 256, 0, stream>>>(Op, Wo16, bo, (float*)d_out, nullptr, NM, NE, NE);
}

// Round 22
// 240.192 us; speedup vs baseline: 1.1205x; 1.1205x over previous
//
#include <hip/hip_runtime.h>

typedef _Float16 f16;
typedef __attribute__((ext_vector_type(2))) __fp16 fp16x2_raw;
typedef __attribute__((ext_vector_type(4))) _Float16 f16x4;
typedef __attribute__((ext_vector_type(8))) _Float16 f16x8;
typedef __attribute__((ext_vector_type(4))) float f32x4;
typedef __attribute__((ext_vector_type(16))) float f32x16;
typedef __attribute__((ext_vector_type(2))) unsigned int u32x2;
typedef __attribute__((ext_vector_type(4))) unsigned int u32x4;

#define NB 4
#define NS 2048
#define NE 1024
#define NH 16
#define ND 64
#define NM (NB*NS)   // 8192 tokens

__device__ __forceinline__ void gld16(const void* g, void* l) {
  __builtin_amdgcn_global_load_lds((const __attribute__((address_space(1))) unsigned int*)g,
                                   (__attribute__((address_space(3))) unsigned int*)l, 16, 0, 0);
}

// pack two f32 -> one u32 of 2 f16 (v_cvt_pkrtz_f16_f32)
__device__ __forceinline__ unsigned cvt2h(float a, float b) {
  fp16x2_raw r = __builtin_amdgcn_cvt_pkrtz(a, b);
  return __builtin_bit_cast(unsigned, r);
}

// proven (R5==R6, distinct-value operands so no reg-coalesce hazard):
// new_a[l] = l<32 ? a[l] : b[l-32]; new_b[l] = l<32 ? a[l+32] : b[l]
__device__ __forceinline__ void plswap(unsigned& a, unsigned& b) {
  asm volatile("v_permlane32_swap_b32 %0, %1" : "+v"(a), "+v"(b));
}
// NOTE: a==b plswap variant miscompiles (R9/R10). Cross-half reductions use __shfl_xor(x,32).

// ---------------- NT GEMM: C = A * B^T + bias ----------------
// R19/R20-proven: single-barrier dbuf + explicit vmcnt(0) drain + XCD-bijective swizzle.
// AF32/BF32: operand is f32 in global, staged via reg-load + cvt_pkrtz + ds_write_b128
// (fused convert — AF32 path proven R20; BF32 is its exact mirror).
template<bool AF32, bool BF32, bool OUTF32>
__global__ __launch_bounds__(256)
void gemm_bt(const void* __restrict__ Asrc, const void* __restrict__ Bsrc,
             const float* __restrict__ bias, float* __restrict__ Cf,
             f16* __restrict__ Ch, int M, int N, int K)
{
  __shared__ __align__(16) f16 As[2*128*32];   // 2 x 8KB
  __shared__ __align__(16) f16 Bs[2*128*32];
  const int t = threadIdx.x;
  const int l = t & 63, w = t >> 6;
  const int wr = w >> 1, wc = w & 1;

  // XCD swizzle: id = (xcd, slot); m_blk = (slot>>3)*8 + xcd, n_blk = slot&7 (bijective, nwg=512)
  const int id = blockIdx.x + blockIdx.y * gridDim.x;
  const int xcd = id & 7, slot = id >> 3;
  const int m0 = (((slot >> 3) << 3) | xcd) * 128;
  const int n0 = (slot & 7) * 128;

  f32x4 acc[4][4];
  #pragma unroll
  for (int i = 0; i < 4; ++i)
    #pragma unroll
    for (int j = 0; j < 4; ++j)
      acc[i][j] = f32x4{0.f, 0.f, 0.f, 0.f};

  const int off0 = (w*2+0)*1024 + l*16;   // byte offsets in one 8KB tile
  const int off1 = (w*2+1)*1024 + l*16;
  const int row0 = off0 >> 6, k0 = (off0 & 63) >> 1;
  const int row1 = off1 >> 6, k1 = (off1 & 63) >> 1;
  const f16*   a0h = (const f16*)Asrc   + (size_t)(m0+row0)*K + k0;
  const f16*   a1h = (const f16*)Asrc   + (size_t)(m0+row1)*K + k1;
  const float* a0f = (const float*)Asrc + (size_t)(m0+row0)*K + k0;
  const float* a1f = (const float*)Asrc + (size_t)(m0+row1)*K + k1;
  const f16*   b0h = (const f16*)Bsrc   + (size_t)(n0+row0)*K + k0;
  const f16*   b1h = (const f16*)Bsrc   + (size_t)(n0+row1)*K + k1;
  const float* b0f = (const float*)Bsrc + (size_t)(n0+row0)*K + k0;
  const float* b1f = (const float*)Bsrc + (size_t)(n0+row1)*K + k1;

  const int aoff = (wr*64 + (l&15))*32 + ((l>>4)<<3);
  const int boff = (wc*64 + (l&15))*32 + ((l>>4)<<3);

  // prologue: stage K-step 0 into buf 0
  if constexpr (BF32) {
    float4 x0 = *(const float4*)(b0f);
    float4 x1 = *(const float4*)(b0f + 4);
    float4 y0 = *(const float4*)(b1f);
    float4 y1 = *(const float4*)(b1f + 4);
    u32x4 wa, wb;
    wa[0] = cvt2h(x0.x, x0.y); wa[1] = cvt2h(x0.z, x0.w);
    wa[2] = cvt2h(x1.x, x1.y); wa[3] = cvt2h(x1.z, x1.w);
    wb[0] = cvt2h(y0.x, y0.y); wb[1] = cvt2h(y0.z, y0.w);
    wb[2] = cvt2h(y1.x, y1.y); wb[3] = cvt2h(y1.z, y1.w);
    *(u32x4*)(Bs + off0/2) = wa;
    *(u32x4*)(Bs + off1/2) = wb;
  } else {
    gld16(b0h, Bs + off0/2);
    gld16(b1h, Bs + off1/2);
  }
  if constexpr (AF32) {
    float4 x0 = *(const float4*)(a0f);
    float4 x1 = *(const float4*)(a0f + 4);
    float4 y0 = *(const float4*)(a1f);
    float4 y1 = *(const float4*)(a1f + 4);
    u32x4 wa, wb;
    wa[0] = cvt2h(x0.x, x0.y); wa[1] = cvt2h(x0.z, x0.w);
    wa[2] = cvt2h(x1.x, x1.y); wa[3] = cvt2h(x1.z, x1.w);
    wb[0] = cvt2h(y0.x, y0.y); wb[1] = cvt2h(y0.z, y0.w);
    wb[2] = cvt2h(y1.x, y1.y); wb[3] = cvt2h(y1.z, y1.w);
    *(u32x4*)(As + off0/2) = wa;
    *(u32x4*)(As + off1/2) = wb;
  } else {
    gld16(a0h, As + off0/2);
    gld16(a1h, As + off1/2);
  }
  asm volatile("s_waitcnt vmcnt(0)" ::: "memory");
  __syncthreads();

  const int NK = K / 32;
  for (int ksi = 0; ksi < NK; ++ksi) {
    const int cur = ksi & 1, nxt = cur ^ 1;
    float4 ax0, ax1, ay0, ay1;
    float4 bx0, bx1, by0, by1;
    if (ksi < NK-1) {
      const int kt = (ksi+1) * 32;
      if constexpr (BF32) {
        bx0 = *(const float4*)(b0f + kt);
        bx1 = *(const float4*)(b0f + kt + 4);
        by0 = *(const float4*)(b1f + kt);
        by1 = *(const float4*)(b1f + kt + 4);
      } else {
        gld16(b0h + kt, Bs + nxt*4096 + off0/2);
        gld16(b1h + kt, Bs + nxt*4096 + off1/2);
      }
      if constexpr (AF32) {
        ax0 = *(const float4*)(a0f + kt);
        ax1 = *(const float4*)(a0f + kt + 4);
        ay0 = *(const float4*)(a1f + kt);
        ay1 = *(const float4*)(a1f + kt + 4);
      } else {
        gld16(a0h + kt, As + nxt*4096 + off0/2);
        gld16(a1h + kt, As + nxt*4096 + off1/2);
      }
    }
    const f16* Ac = As + cur*4096;
    const f16* Bc = Bs + cur*4096;
    f16x8 af[4], bf[4];
    #pragma unroll
    for (int i = 0; i < 4; ++i) af[i] = *(const f16x8*)(Ac + aoff + i*512);
    #pragma unroll
    for (int j = 0; j < 4; ++j) bf[j] = *(const f16x8*)(Bc + boff + j*512);
    #pragma unroll
    for (int i = 0; i < 4; ++i)
      #pragma unroll
      for (int j = 0; j < 4; ++j)
        acc[i][j] = __builtin_amdgcn_mfma_f32_16x16x32_f16(af[i], bf[j], acc[i][j], 0, 0, 0);
    // explicit unconditional drain of this iter's DMAs/loads (R19 doctrine)
    asm volatile("s_waitcnt vmcnt(0)" ::: "memory");
    if (ksi < NK-1) {
      if constexpr (BF32) {
        u32x4 wa, wb;
        wa[0] = cvt2h(bx0.x, bx0.y); wa[1] = cvt2h(bx0.z, bx0.w);
        wa[2] = cvt2h(bx1.x, bx1.y); wa[3] = cvt2h(bx1.z, bx1.w);
        wb[0] = cvt2h(by0.x, by0.y); wb[1] = cvt2h(by0.z, by0.w);
        wb[2] = cvt2h(by1.x, by1.y); wb[3] = cvt2h(by1.z, by1.w);
        *(u32x4*)(Bs + nxt*4096 + off0/2) = wa;
        *(u32x4*)(Bs + nxt*4096 + off1/2) = wb;
      }
      if constexpr (AF32) {
        u32x4 wa, wb;
        wa[0] = cvt2h(ax0.x, ax0.y); wa[1] = cvt2h(ax0.z, ax0.w);
        wa[2] = cvt2h(ax1.x, ax1.y); wa[3] = cvt2h(ax1.z, ax1.w);
        wb[0] = cvt2h(ay0.x, ay0.y); wb[1] = cvt2h(ay0.z, ay0.w);
        wb[2] = cvt2h(ay1.x, ay1.y); wb[3] = cvt2h(ay1.z, ay1.w);
        *(u32x4*)(As + nxt*4096 + off0/2) = wa;
        *(u32x4*)(As + nxt*4096 + off1/2) = wb;
      }
    }
    __syncthreads();
  }

  #pragma unroll
  for (int j = 0; j < 4; ++j) {
    const int col = n0 + wc*64 + j*16 + (l & 15);
    const float bb = bias[col];
    #pragma unroll
    for (int i = 0; i < 4; ++i) {
      const int rowb = m0 + wr*64 + i*16 + ((l>>4)<<2);
      #pragma unroll
      for (int r = 0; r < 4; ++r) {
        float v = acc[i][j][r] + bb;
        if constexpr (OUTF32) Cf[(size_t)(rowb+r)*N + col] = v;
        else                  Ch[(size_t)(rowb+r)*N + col] = (f16)v;
      }
    }
  }
}

// ---------------- flash attention: R15/R20-proven (dbuf + tree-max + split psum + defer-rescale) ----------------
__global__ __launch_bounds__(256, 4)
void attn_kernel(const f16* __restrict__ Q, const f16* __restrict__ K,
                 const f16* __restrict__ V, f16* __restrict__ O)
{
  __shared__ __align__(16) f16 S_lds[16384];

  const int t = threadIdx.x, l = t & 63, w = t >> 6;
  const int lq = l & 31, hi = l >> 5;

  // XCD-bijective swizzle: all 16 q-tiles of one bh on one XCD
  const int lin = blockIdx.x + (blockIdx.y << 4);
  const int xcd = lin & 7, jj = lin >> 3;
  const int bh = xcd * 8 + (jj >> 4);
  const int qt = jj & 15;
  const int b = bh >> 4, h = bh & 15;
  const size_t base = (size_t)b * NS * NE + (size_t)h * ND;
  const int q = qt*128 + w*32 + lq;

  // Q B-fragments
  f16x8 bq[4];
  #pragma unroll
  for (int ks = 0; ks < 4; ++ks)
    bq[ks] = *(const f16x8*)&Q[base + (size_t)q*NE + ks*16 + hi*8];
  asm volatile("s_waitcnt vmcnt(0)" ::: "memory");

  f32x16 o[2];
  #pragma unroll
  for (int dt = 0; dt < 2; ++dt)
    #pragma unroll
    for (int r = 0; r < 16; ++r) o[dt][r] = 0.f;
  float m2 = -3e38f, lsum = 0.f;
  const float K2 = 0.125f * 1.44269504089f;

  // ---- K staging src (inverse-permuted; proven) ----
  const int krow0 = w*16 + (l>>3);
  const int kgran = ((l&7) ^ (l>>3)) * 8;
  const f16* kSrc0 = K + base + (size_t)krow0*NE + kgran;
  const f16* kSrc1 = kSrc0 + (size_t)8*NE;
  // ---- V staging src: lane = key row l, d-chunk = w*16..w*16+15 (proven) ----
  const f16* vSrc = V + base + (size_t)l*NE + w*16;

  const size_t tileAdv = (size_t)64 * NE;
  const int kd0 = (w*2+0)*512 + l*8;
  const int kd1 = (w*2+1)*512 + l*8;

  // ================= prologue: stage tile 0 into buf 0 =================
  f16x8 va, vb;
  {
    gld16(kSrc0, &S_lds[0] + kd0);
    gld16(kSrc1, &S_lds[0] + kd1);
    va = *(const f16x8*)(vSrc);
    vb = *(const f16x8*)(vSrc + 8);
    asm volatile("s_waitcnt vmcnt(0)" ::: "memory");
    char* vt0 = (char*)&S_lds[4096];
    #pragma unroll
    for (int i = 0; i < 8; ++i) {
      const int d0 = w*16 + i, d1 = w*16 + 8 + i;   // d&7 == i&7 for both
      *(f16*)(vt0 + ((d0*128 + l*2) ^ ((i & 7) << 4))) = va[i];
      *(f16*)(vt0 + ((d1*128 + l*2) ^ ((i & 7) << 4))) = vb[i];
    }
  }
  __syncthreads();

  for (int it = 0; it < 32; ++it) {
    const int cur = it & 1, nb = cur ^ 1;
    const char* ksb = (const char*)(&S_lds[cur*8192]);
    const char* vtb = (const char*)(&S_lds[cur*8192 + 4096]);

    // ---- issue next-tile staging loads (overlap with this tile's compute) ----
    if (it < 31) {
      const size_t g = (size_t)(it+1) * tileAdv;
      gld16(kSrc0 + g, &S_lds[nb*8192] + kd0);
      gld16(kSrc1 + g, &S_lds[nb*8192] + kd1);
      va = *(const f16x8*)(vSrc + g);
      vb = *(const f16x8*)(vSrc + g + 8);
    }

    // ---- S^T = K * Q^T ----
    f32x16 s[2];
    #pragma unroll
    for (int ct = 0; ct < 2; ++ct)
      #pragma unroll
      for (int r = 0; r < 16; ++r) s[ct][r] = 0.f;
    __builtin_amdgcn_s_setprio(1);
    #pragma unroll
    for (int ct = 0; ct < 2; ++ct) {
      const int krow = ct*32 + lq;
      const int rswz = (krow & 7) << 4;
      #pragma unroll
      for (int ks = 0; ks < 4; ++ks) {
        f16x8 ak = *(const f16x8*)(ksb + ((krow*128 + ks*32 + hi*16) ^ rswz));
        s[ct] = __builtin_amdgcn_mfma_f32_32x32x16_f16(ak, bq[ks], s[ct], 0, 0, 0);
      }
    }
    __builtin_amdgcn_s_setprio(0);

    // ---- pairwise-tree max (depth 5; exact reassociation) ----
    float mm[16];
    #pragma unroll
    for (int r = 0; r < 16; ++r) mm[r] = fmaxf(s[0][r], s[1][r]);
    #pragma unroll
    for (int st = 8; st > 0; st >>= 1)
      #pragma unroll
      for (int r = 0; r < st; ++r) mm[r] = fmaxf(mm[r], mm[r+st]);
    float mx = mm[0] * K2;
    mx = fmaxf(mx, __shfl_xor(mx, 32));

    // ---- defer-rescale (T13, THR=8 in log2) ----
    if (__any(mx > m2 + 8.0f)) {
      const float mnew = fmaxf(m2, mx);
      const float alpha = __builtin_amdgcn_exp2f(m2 - mnew);
      m2 = mnew;
      lsum *= alpha;
      #pragma unroll
      for (int dt = 0; dt < 2; ++dt)
        #pragma unroll
        for (int r = 0; r < 16; ++r) o[dt][r] *= alpha;
    }

    // ---- exp + 4-way split psum ----
    float ps4[4] = {0.f, 0.f, 0.f, 0.f};
    #pragma unroll
    for (int ct = 0; ct < 2; ++ct)
      #pragma unroll
      for (int r = 0; r < 16; ++r) {
        float p = __builtin_amdgcn_exp2f(s[ct][r]*K2 - m2);
        s[ct][r] = p;
        ps4[r & 3] += p;
      }
    lsum += (ps4[0] + ps4[1]) + (ps4[2] + ps4[3]);

    // ---- pack P, build PV B-operands via plswap (distinct values: proven) ----
    f16x8 pa[4];
    #pragma unroll
    for (int ct = 0; ct < 2; ++ct) {
      unsigned wd[8];
      #pragma unroll
      for (int m = 0; m < 4; ++m)
        #pragma unroll
        for (int hh = 0; hh < 2; ++hh)
          wd[m*2 + hh] = cvt2h(s[ct][4*m + 2*hh], s[ct][4*m + 2*hh + 1]);
      #pragma unroll
      for (int ks2 = 0; ks2 < 2; ++ks2) {
        unsigned a0 = wd[(2*ks2)*2 + 0], b0 = wd[(2*ks2+1)*2 + 0];
        unsigned a1 = wd[(2*ks2)*2 + 1], b1 = wd[(2*ks2+1)*2 + 1];
        plswap(a0, b0);
        plswap(a1, b1);
        union { unsigned u[4]; f16x8 v; } pp;
        pp.u[0] = a0; pp.u[1] = a1; pp.u[2] = b0; pp.u[3] = b1;
        pa[ct*2 + ks2] = pp.v;
      }
    }

    // ---- O^T += V^T * P ----
    __builtin_amdgcn_s_setprio(1);
    #pragma unroll
    for (int ks = 0; ks < 4; ++ks)
      #pragma unroll
      for (int dt = 0; dt < 2; ++dt) {
        const int drow = dt*32 + lq;
        f16x8 av = *(const f16x8*)(vtb + ((drow*128 + ks*32 + hi*16) ^ ((drow & 7) << 4)));
        o[dt] = __builtin_amdgcn_mfma_f32_32x32x16_f16(av, pa[ks], o[dt], 0, 0, 0);
      }
    __builtin_amdgcn_s_setprio(0);

    // ---- finish staging next tile: drain loads, write Vt, single barrier ----
    if (it < 31) {
      asm volatile("s_waitcnt vmcnt(0)" ::: "memory");
      char* vtn = (char*)(&S_lds[nb*8192 + 4096]);
      #pragma unroll
      for (int i = 0; i < 8; ++i) {
        const int d0 = w*16 + i, d1 = w*16 + 8 + i;
        *(f16*)(vtn + ((d0*128 + l*2) ^ ((i & 7) << 4))) = va[i];
        *(f16*)(vtn + ((d1*128 + l*2) ^ ((i & 7) << 4))) = vb[i];
      }
      __syncthreads();
    }
  }

  // ---- epilogue: cross-half lsum combine (shfl, proven), normalize, store ----
  const float lt = lsum + __shfl_xor(lsum, 32);
  const float linv = 1.0f / lt;
  #pragma unroll
  for (int dt = 0; dt < 2; ++dt)
    #pragma unroll
    for (int m = 0; m < 4; ++m) {
      u32x2 st;
      st.x = cvt2h(o[dt][4*m+0]*linv, o[dt][4*m+1]*linv);
      st.y = cvt2h(o[dt][4*m+2]*linv, o[dt][4*m+3]*linv);
      const int d = dt*32 + 8*m + 4*hi;
      *(u32x2*)&O[base + (size_t)q*NE + d] = st;
    }
}

// ---------------- launch ----------------
extern "C" void kernel_launch(void* const* d_in, const int* in_sizes, int n_in,
                              void* d_out, int out_size, void* d_ws, size_t ws_size,
                              hipStream_t stream)
{
  const float* q_in = (const float*)d_in[0];
  const float* k_in = (const float*)d_in[1];
  const float* v_in = (const float*)d_in[2];
  const float* Wq = (const float*)d_in[3];
  const float* bq = (const float*)d_in[4];
  const float* Wk = (const float*)d_in[5];
  const float* bk = (const float*)d_in[6];
  const float* Wv = (const float*)d_in[7];
  const float* bv = (const float*)d_in[8];
  const float* Wo = (const float*)d_in[9];
  const float* bo = (const float*)d_in[10];

  char* ws = (char*)d_ws;
  f16* Qp   = (f16*)(ws + 58720256);
  f16* Kp   = (f16*)(ws + 75497472);
  f16* Vp   = (f16*)(ws + 92274688);
  f16* Op   = (f16*)(ws + 109051904);

  dim3 gg(8, 64);
  gemm_bt<true,  true,  false><<<gg, 256, 0, stream>>>(q_in, Wq, bq, nullptr, Qp, NM, NE, NE);
  gemm_bt<true,  true,  false><<<gg, 256, 0, stream>>>(k_in, Wk, bk, nullptr, Kp, NM, NE, NE);
  gemm_bt<true,  true,  false><<<gg, 256, 0, stream>>>(v_in, Wv, bv, nullptr, Vp, NM, NE, NE);

  attn_kernel<<<dim3(16, 64), 256, 0, stream>>>(Qp, Kp, Vp, Op);

  gemm_bt<false, true,  true><<<gg, 256, 0, stream>>>(Op, Wo, bo, (float*)d_out, nullptr, NM, NE, NE);
}

// Round 23
// 234.720 us; speedup vs baseline: 1.1466x; 1.0233x over previous
//
#include <hip/hip_runtime.h>

typedef _Float16 f16;
typedef __attribute__((ext_vector_type(2))) __fp16 fp16x2_raw;
typedef __attribute__((ext_vector_type(4))) _Float16 f16x4;
typedef __attribute__((ext_vector_type(8))) _Float16 f16x8;
typedef __attribute__((ext_vector_type(4))) float f32x4;
typedef __attribute__((ext_vector_type(16))) float f32x16;
typedef __attribute__((ext_vector_type(2))) unsigned int u32x2;
typedef __attribute__((ext_vector_type(4))) unsigned int u32x4;

#define NB 4
#define NS 2048
#define NE 1024
#define NH 16
#define ND 64
#define NM (NB*NS)   // 8192 tokens

__device__ __forceinline__ void gld16(const void* g, void* l) {
  __builtin_amdgcn_global_load_lds((const __attribute__((address_space(1))) unsigned int*)g,
                                   (__attribute__((address_space(3))) unsigned int*)l, 16, 0, 0);
}

// pack two f32 -> one u32 of 2 f16 (v_cvt_pkrtz_f16_f32)
__device__ __forceinline__ unsigned cvt2h(float a, float b) {
  fp16x2_raw r = __builtin_amdgcn_cvt_pkrtz(a, b);
  return __builtin_bit_cast(unsigned, r);
}

// proven (R5==R6, distinct-value operands so no reg-coalesce hazard):
// new_a[l] = l<32 ? a[l] : b[l-32]; new_b[l] = l<32 ? a[l+32] : b[l]
__device__ __forceinline__ void plswap(unsigned& a, unsigned& b) {
  asm volatile("v_permlane32_swap_b32 %0, %1" : "+v"(a), "+v"(b));
}
// NOTE: a==b plswap variant miscompiles (R9/R10). Cross-half reductions use __shfl_xor(x,32).

// ---------------- GEMM body (R19/R22-proven): dbuf + explicit drain + XCD swizzle ----------------
// A f32 (fused convert), B f32 (fused convert); C written f16 or f32.
template<bool AF32, bool BF32, bool OUTF32>
__device__ __forceinline__
void gemm_body(const void* __restrict__ Asrc, const void* __restrict__ Bsrc,
               const float* __restrict__ bias, float* __restrict__ Cf,
               f16* __restrict__ Ch, int M, int N, int K, int id,
               f16* As, f16* Bs)
{
  const int t = threadIdx.x;
  const int l = t & 63, w = t >> 6;
  const int wr = w >> 1, wc = w & 1;

  // XCD swizzle: id = (xcd, slot); m_blk = (slot>>3)*8 + xcd, n_blk = slot&7 (bijective, nwg=512)
  const int xcd = id & 7, slot = id >> 3;
  const int m0 = (((slot >> 3) << 3) | xcd) * 128;
  const int n0 = (slot & 7) * 128;

  f32x4 acc[4][4];
  #pragma unroll
  for (int i = 0; i < 4; ++i)
    #pragma unroll
    for (int j = 0; j < 4; ++j)
      acc[i][j] = f32x4{0.f, 0.f, 0.f, 0.f};

  const int off0 = (w*2+0)*1024 + l*16;   // byte offsets in one 8KB tile
  const int off1 = (w*2+1)*1024 + l*16;
  const int row0 = off0 >> 6, k0 = (off0 & 63) >> 1;
  const int row1 = off1 >> 6, k1 = (off1 & 63) >> 1;
  const f16*   a0h = (const f16*)Asrc   + (size_t)(m0+row0)*K + k0;
  const f16*   a1h = (const f16*)Asrc   + (size_t)(m0+row1)*K + k1;
  const float* a0f = (const float*)Asrc + (size_t)(m0+row0)*K + k0;
  const float* a1f = (const float*)Asrc + (size_t)(m0+row1)*K + k1;
  const float* b0f = (const float*)Bsrc + (size_t)(n0+row0)*K + k0;
  const float* b1f = (const float*)Bsrc + (size_t)(n0+row1)*K + k1;

  const int aoff = (wr*64 + (l&15))*32 + ((l>>4)<<3);
  const int boff = (wc*64 + (l&15))*32 + ((l>>4)<<3);

  // prologue: stage K-step 0 into buf 0
  {
    float4 x0 = *(const float4*)(b0f);
    float4 x1 = *(const float4*)(b0f + 4);
    float4 y0 = *(const float4*)(b1f);
    float4 y1 = *(const float4*)(b1f + 4);
    u32x4 wa, wb;
    wa[0] = cvt2h(x0.x, x0.y); wa[1] = cvt2h(x0.z, x0.w);
    wa[2] = cvt2h(x1.x, x1.y); wa[3] = cvt2h(x1.z, x1.w);
    wb[0] = cvt2h(y0.x, y0.y); wb[1] = cvt2h(y0.z, y0.w);
    wb[2] = cvt2h(y1.x, y1.y); wb[3] = cvt2h(y1.z, y1.w);
    *(u32x4*)(Bs + off0/2) = wa;
    *(u32x4*)(Bs + off1/2) = wb;
  }
  if constexpr (AF32) {
    float4 x0 = *(const float4*)(a0f);
    float4 x1 = *(const float4*)(a0f + 4);
    float4 y0 = *(const float4*)(a1f);
    float4 y1 = *(const float4*)(a1f + 4);
    u32x4 wa, wb;
    wa[0] = cvt2h(x0.x, x0.y); wa[1] = cvt2h(x0.z, x0.w);
    wa[2] = cvt2h(x1.x, x1.y); wa[3] = cvt2h(x1.z, x1.w);
    wb[0] = cvt2h(y0.x, y0.y); wb[1] = cvt2h(y0.z, y0.w);
    wb[2] = cvt2h(y1.x, y1.y); wb[3] = cvt2h(y1.z, y1.w);
    *(u32x4*)(As + off0/2) = wa;
    *(u32x4*)(As + off1/2) = wb;
  } else {
    gld16(a0h, As + off0/2);
    gld16(a1h, As + off1/2);
  }
  asm volatile("s_waitcnt vmcnt(0)" ::: "memory");
  __syncthreads();

  const int NK = K / 32;
  for (int ksi = 0; ksi < NK; ++ksi) {
    const int cur = ksi & 1, nxt = cur ^ 1;
    float4 ax0, ax1, ay0, ay1;
    float4 bx0, bx1, by0, by1;
    if (ksi < NK-1) {
      const int kt = (ksi+1) * 32;
      bx0 = *(const float4*)(b0f + kt);
      bx1 = *(const float4*)(b0f + kt + 4);
      by0 = *(const float4*)(b1f + kt);
      by1 = *(const float4*)(b1f + kt + 4);
      if constexpr (AF32) {
        ax0 = *(const float4*)(a0f + kt);
        ax1 = *(const float4*)(a0f + kt + 4);
        ay0 = *(const float4*)(a1f + kt);
        ay1 = *(const float4*)(a1f + kt + 4);
      } else {
        gld16(a0h + kt, As + nxt*4096 + off0/2);
        gld16(a1h + kt, As + nxt*4096 + off1/2);
      }
    }
    const f16* Ac = As + cur*4096;
    const f16* Bc = Bs + cur*4096;
    f16x8 af[4], bf[4];
    #pragma unroll
    for (int i = 0; i < 4; ++i) af[i] = *(const f16x8*)(Ac + aoff + i*512);
    #pragma unroll
    for (int j = 0; j < 4; ++j) bf[j] = *(const f16x8*)(Bc + boff + j*512);
    #pragma unroll
    for (int i = 0; i < 4; ++i)
      #pragma unroll
      for (int j = 0; j < 4; ++j)
        acc[i][j] = __builtin_amdgcn_mfma_f32_16x16x32_f16(af[i], bf[j], acc[i][j], 0, 0, 0);
    // explicit unconditional drain of this iter's DMAs/loads (R19 doctrine)
    asm volatile("s_waitcnt vmcnt(0)" ::: "memory");
    if (ksi < NK-1) {
      {
        u32x4 wa, wb;
        wa[0] = cvt2h(bx0.x, bx0.y); wa[1] = cvt2h(bx0.z, bx0.w);
        wa[2] = cvt2h(bx1.x, bx1.y); wa[3] = cvt2h(bx1.z, bx1.w);
        wb[0] = cvt2h(by0.x, by0.y); wb[1] = cvt2h(by0.z, by0.w);
        wb[2] = cvt2h(by1.x, by1.y); wb[3] = cvt2h(by1.z, by1.w);
        *(u32x4*)(Bs + nxt*4096 + off0/2) = wa;
        *(u32x4*)(Bs + nxt*4096 + off1/2) = wb;
      }
      if constexpr (AF32) {
        u32x4 wa, wb;
        wa[0] = cvt2h(ax0.x, ax0.y); wa[1] = cvt2h(ax0.z, ax0.w);
        wa[2] = cvt2h(ax1.x, ax1.y); wa[3] = cvt2h(ax1.z, ax1.w);
        wb[0] = cvt2h(ay0.x, ay0.y); wb[1] = cvt2h(ay0.z, ay0.w);
        wb[2] = cvt2h(ay1.x, ay1.y); wb[3] = cvt2h(ay1.z, ay1.w);
        *(u32x4*)(As + nxt*4096 + off0/2) = wa;
        *(u32x4*)(As + nxt*4096 + off1/2) = wb;
      }
    }
    __syncthreads();
  }

  #pragma unroll
  for (int j = 0; j < 4; ++j) {
    const int col = n0 + wc*64 + j*16 + (l & 15);
    const float bb = bias[col];
    #pragma unroll
    for (int i = 0; i < 4; ++i) {
      const int rowb = m0 + wr*64 + i*16 + ((l>>4)<<2);
      #pragma unroll
      for (int r = 0; r < 4; ++r) {
        float v = acc[i][j][r] + bb;
        if constexpr (OUTF32) Cf[(size_t)(rowb+r)*N + col] = v;
        else                  Ch[(size_t)(rowb+r)*N + col] = (f16)v;
      }
    }
  }
}

// ---------------- batched QKV GEMM: grid (8,64,3), z selects {q,k,v} ----------------
__global__ __launch_bounds__(256)
void gemm_qkv(const float* __restrict__ q_in, const float* __restrict__ k_in,
              const float* __restrict__ v_in, const float* __restrict__ Wq,
              const float* __restrict__ Wk, const float* __restrict__ Wv,
              const float* __restrict__ bq, const float* __restrict__ bk,
              const float* __restrict__ bv, f16* __restrict__ Qp,
              f16* __restrict__ Kp, f16* __restrict__ Vp)
{
  __shared__ __align__(16) f16 As[2*128*32];
  __shared__ __align__(16) f16 Bs[2*128*32];
  const int z = blockIdx.z;
  const float* Asrc = (z == 0) ? q_in : (z == 1) ? k_in : v_in;
  const float* Bsrc = (z == 0) ? Wq : (z == 1) ? Wk : Wv;
  const float* bias = (z == 0) ? bq : (z == 1) ? bk : bv;
  f16* Ch = (z == 0) ? Qp : (z == 1) ? Kp : Vp;
  const int id = blockIdx.x + blockIdx.y * gridDim.x;
  gemm_body<true, true, false>(Asrc, Bsrc, bias, nullptr, Ch, NM, NE, NE, id, As, Bs);
}

// ---------------- Wo GEMM: A f16 (attn out), B f32 weights, C f32 ----------------
__global__ __launch_bounds__(256)
void gemm_out(const f16* __restrict__ Op, const float* __restrict__ Wo,
              const float* __restrict__ bo, float* __restrict__ Out)
{
  __shared__ __align__(16) f16 As[2*128*32];
  __shared__ __align__(16) f16 Bs[2*128*32];
  const int id = blockIdx.x + blockIdx.y * gridDim.x;
  gemm_body<false, true, true>(Op, Wo, bo, Out, nullptr, NM, NE, NE, id, As, Bs);
}

// ---------------- flash attention: R15/R20-proven (dbuf + tree-max + split psum + defer-rescale) ----------------
__global__ __launch_bounds__(256, 4)
void attn_kernel(const f16* __restrict__ Q, const f16* __restrict__ K,
                 const f16* __restrict__ V, f16* __restrict__ O)
{
  __shared__ __align__(16) f16 S_lds[16384];

  const int t = threadIdx.x, l = t & 63, w = t >> 6;
  const int lq = l & 31, hi = l >> 5;

  // XCD-bijective swizzle: all 16 q-tiles of one bh on one XCD
  const int lin = blockIdx.x + (blockIdx.y << 4);
  const int xcd = lin & 7, jj = lin >> 3;
  const int bh = xcd * 8 + (jj >> 4);
  const int qt = jj & 15;
  const int b = bh >> 4, h = bh & 15;
  const size_t base = (size_t)b * NS * NE + (size_t)h * ND;
  const int q = qt*128 + w*32 + lq;

  // Q B-fragments
  f16x8 bq[4];
  #pragma unroll
  for (int ks = 0; ks < 4; ++ks)
    bq[ks] = *(const f16x8*)&Q[base + (size_t)q*NE + ks*16 + hi*8];
  asm volatile("s_waitcnt vmcnt(0)" ::: "memory");

  f32x16 o[2];
  #pragma unroll
  for (int dt = 0; dt < 2; ++dt)
    #pragma unroll
    for (int r = 0; r < 16; ++r) o[dt][r] = 0.f;
  float m2 = -3e38f, lsum = 0.f;
  const float K2 = 0.125f * 1.44269504089f;

  // ---- K staging src (inverse-permuted; proven) ----
  const int krow0 = w*16 + (l>>3);
  const int kgran = ((l&7) ^ (l>>3)) * 8;
  const f16* kSrc0 = K + base + (size_t)krow0*NE + kgran;
  const f16* kSrc1 = kSrc0 + (size_t)8*NE;
  // ---- V staging src: lane = key row l, d-chunk = w*16..w*16+15 (proven) ----
  const f16* vSrc = V + base + (size_t)l*NE + w*16;

  const size_t tileAdv = (size_t)64 * NE;
  const int kd0 = (w*2+0)*512 + l*8;
  const int kd1 = (w*2+1)*512 + l*8;

  // ================= prologue: stage tile 0 into buf 0 =================
  f16x8 va, vb;
  {
    gld16(kSrc0, &S_lds[0] + kd0);
    gld16(kSrc1, &S_lds[0] + kd1);
    va = *(const f16x8*)(vSrc);
    vb = *(const f16x8*)(vSrc + 8);
    asm volatile("s_waitcnt vmcnt(0)" ::: "memory");
    char* vt0 = (char*)&S_lds[4096];
    #pragma unroll
    for (int i = 0; i < 8; ++i) {
      const int d0 = w*16 + i, d1 = w*16 + 8 + i;   // d&7 == i&7 for both
      *(f16*)(vt0 + ((d0*128 + l*2) ^ ((i & 7) << 4))) = va[i];
      *(f16*)(vt0 + ((d1*128 + l*2) ^ ((i & 7) << 4))) = vb[i];
    }
  }
  __syncthreads();

  for (int it = 0; it < 32; ++it) {
    const int cur = it & 1, nb = cur ^ 1;
    const char* ksb = (const char*)(&S_lds[cur*8192]);
    const char* vtb = (const char*)(&S_lds[cur*8192 + 4096]);

    // ---- issue next-tile staging loads (overlap with this tile's compute) ----
    if (it < 31) {
      const size_t g = (size_t)(it+1) * tileAdv;
      gld16(kSrc0 + g, &S_lds[nb*8192] + kd0);
      gld16(kSrc1 + g, &S_lds[nb*8192] + kd1);
      va = *(const f16x8*)(vSrc + g);
      vb = *(const f16x8*)(vSrc + g + 8);
    }

    // ---- S^T = K * Q^T ----
    f32x16 s[2];
    #pragma unroll
    for (int ct = 0; ct < 2; ++ct)
      #pragma unroll
      for (int r = 0; r < 16; ++r) s[ct][r] = 0.f;
    __builtin_amdgcn_s_setprio(1);
    #pragma unroll
    for (int ct = 0; ct < 2; ++ct) {
      const int krow = ct*32 + lq;
      const int rswz = (krow & 7) << 4;
      #pragma unroll
      for (int ks = 0; ks < 4; ++ks) {
        f16x8 ak = *(const f16x8*)(ksb + ((krow*128 + ks*32 + hi*16) ^ rswz));
        s[ct] = __builtin_amdgcn_mfma_f32_32x32x16_f16(ak, bq[ks], s[ct], 0, 0, 0);
      }
    }
    __builtin_amdgcn_s_setprio(0);

    // ---- pairwise-tree max (depth 5; exact reassociation) ----
    float mm[16];
    #pragma unroll
    for (int r = 0; r < 16; ++r) mm[r] = fmaxf(s[0][r], s[1][r]);
    #pragma unroll
    for (int st = 8; st > 0; st >>= 1)
      #pragma unroll
      for (int r = 0; r < st; ++r) mm[r] = fmaxf(mm[r], mm[r+st]);
    float mx = mm[0] * K2;
    mx = fmaxf(mx, __shfl_xor(mx, 32));

    // ---- defer-rescale (T13, THR=8 in log2) ----
    if (__any(mx > m2 + 8.0f)) {
      const float mnew = fmaxf(m2, mx);
      const float alpha = __builtin_amdgcn_exp2f(m2 - mnew);
      m2 = mnew;
      lsum *= alpha;
      #pragma unroll
      for (int dt = 0; dt < 2; ++dt)
        #pragma unroll
        for (int r = 0; r < 16; ++r) o[dt][r] *= alpha;
    }

    // ---- exp + 4-way split psum ----
    float ps4[4] = {0.f, 0.f, 0.f, 0.f};
    #pragma unroll
    for (int ct = 0; ct < 2; ++ct)
      #pragma unroll
      for (int r = 0; r < 16; ++r) {
        float p = __builtin_amdgcn_exp2f(s[ct][r]*K2 - m2);
        s[ct][r] = p;
        ps4[r & 3] += p;
      }
    lsum += (ps4[0] + ps4[1]) + (ps4[2] + ps4[3]);

    // ---- pack P, build PV B-operands via plswap (distinct values: proven) ----
    f16x8 pa[4];
    #pragma unroll
    for (int ct = 0; ct < 2; ++ct) {
      unsigned wd[8];
      #pragma unroll
      for (int m = 0; m < 4; ++m)
        #pragma unroll
        for (int hh = 0; hh < 2; ++hh)
          wd[m*2 + hh] = cvt2h(s[ct][4*m + 2*hh], s[ct][4*m + 2*hh + 1]);
      #pragma unroll
      for (int ks2 = 0; ks2 < 2; ++ks2) {
        unsigned a0 = wd[(2*ks2)*2 + 0], b0 = wd[(2*ks2+1)*2 + 0];
        unsigned a1 = wd[(2*ks2)*2 + 1], b1 = wd[(2*ks2+1)*2 + 1];
        plswap(a0, b0);
        plswap(a1, b1);
        union { unsigned u[4]; f16x8 v; } pp;
        pp.u[0] = a0; pp.u[1] = a1; pp.u[2] = b0; pp.u[3] = b1;
        pa[ct*2 + ks2] = pp.v;
      }
    }

    // ---- O^T += V^T * P ----
    __builtin_amdgcn_s_setprio(1);
    #pragma unroll
    for (int ks = 0; ks < 4; ++ks)
      #pragma unroll
      for (int dt = 0; dt < 2; ++dt) {
        const int drow = dt*32 + lq;
        f16x8 av = *(const f16x8*)(vtb + ((drow*128 + ks*32 + hi*16) ^ ((drow & 7) << 4)));
        o[dt] = __builtin_amdgcn_mfma_f32_32x32x16_f16(av, pa[ks], o[dt], 0, 0, 0);
      }
    __builtin_amdgcn_s_setprio(0);

    // ---- finish staging next tile: drain loads, write Vt, single barrier ----
    if (it < 31) {
      asm volatile("s_waitcnt vmcnt(0)" ::: "memory");
      char* vtn = (char*)(&S_lds[nb*8192 + 4096]);
      #pragma unroll
      for (int i = 0; i < 8; ++i) {
        const int d0 = w*16 + i, d1 = w*16 + 8 + i;
        *(f16*)(vtn + ((d0*128 + l*2) ^ ((i & 7) << 4))) = va[i];
        *(f16*)(vtn + ((d1*128 + l*2) ^ ((i & 7) << 4))) = vb[i];
      }
      __syncthreads();
    }
  }

  // ---- epilogue: cross-half lsum combine (shfl, proven), normalize, store ----
  const float lt = lsum + __shfl_xor(lsum, 32);
  const float linv = 1.0f / lt;
  #pragma unroll
  for (int dt = 0; dt < 2; ++dt)
    #pragma unroll
    for (int m = 0; m < 4; ++m) {
      u32x2 st;
      st.x = cvt2h(o[dt][4*m+0]*linv, o[dt][4*m+1]*linv);
      st.y = cvt2h(o[dt][4*m+2]*linv, o[dt][4*m+3]*linv);
      const int d = dt*32 + 8*m + 4*hi;
      *(u32x2*)&O[base + (size_t)q*NE + d] = st;
    }
}

// ---------------- launch ----------------
extern "C" void kernel_launch(void* const* d_in, const int* in_sizes, int n_in,
                              void* d_out, int out_size, void* d_ws, size_t ws_size,
                              hipStream_t stream)
{
  const float* q_in = (const float*)d_in[0];
  const float* k_in = (const float*)d_in[1];
  const float* v_in = (const float*)d_in[2];
  const float* Wq = (const float*)d_in[3];
  const float* bq = (const float*)d_in[4];
  const float* Wk = (const float*)d_in[5];
  const float* bk = (const float*)d_in[6];
  const float* Wv = (const float*)d_in[7];
  const float* bv = (const float*)d_in[8];
  const float* Wo = (const float*)d_in[9];
  const float* bo = (const float*)d_in[10];

  char* ws = (char*)d_ws;
  f16* Qp   = (f16*)(ws + 58720256);
  f16* Kp   = (f16*)(ws + 75497472);
  f16* Vp   = (f16*)(ws + 92274688);
  f16* Op   = (f16*)(ws + 109051904);

  gemm_qkv<<<dim3(8, 64, 3), 256, 0, stream>>>(q_in, k_in, v_in, Wq, Wk, Wv,
                                               bq, bk, bv, Qp, Kp, Vp);

  attn_kernel<<<dim3(16, 64), 256, 0, stream>>>(Qp, Kp, Vp, Op);

  gemm_out<<<dim3(8, 64), 256, 0, stream>>>(Op, Wo, bo, (float*)d_out);
}

// Round 24
// 218.596 us; speedup vs baseline: 1.2312x; 1.0738x over previous
//
#include <hip/hip_runtime.h>

typedef _Float16 f16;
typedef __attribute__((ext_vector_type(2))) __fp16 fp16x2_raw;
typedef __attribute__((ext_vector_type(4))) _Float16 f16x4;
typedef __attribute__((ext_vector_type(8))) _Float16 f16x8;
typedef __attribute__((ext_vector_type(4))) float f32x4;
typedef __attribute__((ext_vector_type(16))) float f32x16;
typedef __attribute__((ext_vector_type(2))) unsigned int u32x2;
typedef __attribute__((ext_vector_type(4))) unsigned int u32x4;

#define NB 4
#define NS 2048
#define NE 1024
#define NH 16
#define ND 64
#define NM (NB*NS)   // 8192 tokens

__device__ __forceinline__ void gld16(const void* g, void* l) {
  __builtin_amdgcn_global_load_lds((const __attribute__((address_space(1))) unsigned int*)g,
                                   (__attribute__((address_space(3))) unsigned int*)l, 16, 0, 0);
}

// pack two f32 -> one u32 of 2 f16 (v_cvt_pkrtz_f16_f32)
__device__ __forceinline__ unsigned cvt2h(float a, float b) {
  fp16x2_raw r = __builtin_amdgcn_cvt_pkrtz(a, b);
  return __builtin_bit_cast(unsigned, r);
}

// proven (R5==R6, distinct-value operands so no reg-coalesce hazard):
// new_a[l] = l<32 ? a[l] : b[l-32]; new_b[l] = l<32 ? a[l+32] : b[l]
__device__ __forceinline__ void plswap(unsigned& a, unsigned& b) {
  asm volatile("v_permlane32_swap_b32 %0, %1" : "+v"(a), "+v"(b));
}
// NOTE: a==b plswap variant miscompiles (R9/R10). Cross-half reductions use __shfl_xor(x,32).

__device__ __forceinline__ u32x4 pack8(float4 x0, float4 x1) {
  u32x4 r;
  r[0] = cvt2h(x0.x, x0.y); r[1] = cvt2h(x0.z, x0.w);
  r[2] = cvt2h(x1.x, x1.y); r[3] = cvt2h(x1.z, x1.w);
  return r;
}

// ---------------- GEMM body: depth-2 pipelined, all operands reg-staged ----------------
// R19-proven barrier structure (one barrier/step, write buf[(k+1)&1] after compute of buf[k&1]);
// depth-2 prefetch: loads for step k+2 issued at step k, consumed (cvt+ds_write) at step k+1.
// No DMAs -> compiler's register-dependency waits are sufficient; no explicit vmcnt needed.
template<bool AF32, bool OUTF32>
__device__ __forceinline__
void gemm_body(const void* __restrict__ Asrc, const float* __restrict__ Bsrc,
               const float* __restrict__ bias, float* __restrict__ Cf,
               f16* __restrict__ Ch, int id, f16* As, f16* Bs)
{
  const int K = NE, N = NE;
  const int t = threadIdx.x;
  const int l = t & 63, w = t >> 6;
  const int wr = w >> 1, wc = w & 1;

  // XCD swizzle: id = (xcd, slot); m_blk = (slot>>3)*8 + xcd, n_blk = slot&7 (bijective, nwg=512)
  const int xcd = id & 7, slot = id >> 3;
  const int m0 = (((slot >> 3) << 3) | xcd) * 128;
  const int n0 = (slot & 7) * 128;

  f32x4 acc[4][4];
  #pragma unroll
  for (int i = 0; i < 4; ++i)
    #pragma unroll
    for (int j = 0; j < 4; ++j)
      acc[i][j] = f32x4{0.f, 0.f, 0.f, 0.f};

  const int off0 = (w*2+0)*1024 + l*16;   // byte offsets in one 8KB tile
  const int off1 = (w*2+1)*1024 + l*16;
  const int row0 = off0 >> 6, k0 = (off0 & 63) >> 1;
  const int row1 = off1 >> 6, k1 = (off1 & 63) >> 1;
  const f16*   a0h = (const f16*)Asrc   + (size_t)(m0+row0)*K + k0;
  const f16*   a1h = (const f16*)Asrc   + (size_t)(m0+row1)*K + k1;
  const float* a0f = (const float*)Asrc + (size_t)(m0+row0)*K + k0;
  const float* a1f = (const float*)Asrc + (size_t)(m0+row1)*K + k1;
  const float* b0f = Bsrc + (size_t)(n0+row0)*K + k0;
  const float* b1f = Bsrc + (size_t)(n0+row1)*K + k1;

  const int aoff = (wr*64 + (l&15))*32 + ((l>>4)<<3);
  const int boff = (wc*64 + (l&15))*32 + ((l>>4)<<3);

  // pend sets: B as float4 quads; A as float4 quads (AF32) or f16x8 pairs
  float4 B0x0, B0x1, B0y0, B0y1, B1x0, B1x1, B1y0, B1y1;
  float4 A0x0, A0x1, A0y0, A0y1, A1x0, A1x1, A1y0, A1y1;
  f16x8  H0a, H0b, H1a, H1b;

  // ---- prologue: step 0 staged directly; pend set1 = step 1 ----
  {
    B0x0 = *(const float4*)(b0f);     B0x1 = *(const float4*)(b0f + 4);
    B0y0 = *(const float4*)(b1f);     B0y1 = *(const float4*)(b1f + 4);
    *(u32x4*)(Bs + off0/2) = pack8(B0x0, B0x1);
    *(u32x4*)(Bs + off1/2) = pack8(B0y0, B0y1);
    if constexpr (AF32) {
      A0x0 = *(const float4*)(a0f);   A0x1 = *(const float4*)(a0f + 4);
      A0y0 = *(const float4*)(a1f);   A0y1 = *(const float4*)(a1f + 4);
      *(u32x4*)(As + off0/2) = pack8(A0x0, A0x1);
      *(u32x4*)(As + off1/2) = pack8(A0y0, A0y1);
    } else {
      H0a = *(const f16x8*)(a0h);     H0b = *(const f16x8*)(a1h);
      *(f16x8*)(As + off0/2) = H0a;
      *(f16x8*)(As + off1/2) = H0b;
    }
    // pend for step 1
    B1x0 = *(const float4*)(b0f + 32);  B1x1 = *(const float4*)(b0f + 36);
    B1y0 = *(const float4*)(b1f + 32);  B1y1 = *(const float4*)(b1f + 36);
    if constexpr (AF32) {
      A1x0 = *(const float4*)(a0f + 32);  A1x1 = *(const float4*)(a0f + 36);
      A1y0 = *(const float4*)(a1f + 32);  A1y1 = *(const float4*)(a1f + 36);
    } else {
      H1a = *(const f16x8*)(a0h + 32);    H1b = *(const f16x8*)(a1h + 32);
    }
  }
  __syncthreads();

  #define GB_COMPUTE(BUFOFF)                                                     \
    {                                                                            \
      const f16* Ac = As + (BUFOFF);                                             \
      const f16* Bc = Bs + (BUFOFF);                                             \
      f16x8 af[4], bf[4];                                                        \
      _Pragma("unroll")                                                          \
      for (int i = 0; i < 4; ++i) af[i] = *(const f16x8*)(Ac + aoff + i*512);    \
      _Pragma("unroll")                                                          \
      for (int j = 0; j < 4; ++j) bf[j] = *(const f16x8*)(Bc + boff + j*512);    \
      _Pragma("unroll")                                                          \
      for (int i = 0; i < 4; ++i)                                                \
        _Pragma("unroll")                                                        \
        for (int j = 0; j < 4; ++j)                                              \
          acc[i][j] = __builtin_amdgcn_mfma_f32_16x16x32_f16(af[i], bf[j], acc[i][j], 0, 0, 0); \
    }

  for (int ksi = 0; ksi < 32; ksi += 2) {
    // ===== EVEN: compute step ksi from buf0 =====
    const bool ld0 = (ksi + 2 < 32);
    if (ld0) {
      const int kt = (ksi + 2) * 32;
      B0x0 = *(const float4*)(b0f + kt);  B0x1 = *(const float4*)(b0f + kt + 4);
      B0y0 = *(const float4*)(b1f + kt);  B0y1 = *(const float4*)(b1f + kt + 4);
      if constexpr (AF32) {
        A0x0 = *(const float4*)(a0f + kt);  A0x1 = *(const float4*)(a0f + kt + 4);
        A0y0 = *(const float4*)(a1f + kt);  A0y1 = *(const float4*)(a1f + kt + 4);
      } else {
        H0a = *(const f16x8*)(a0h + kt);    H0b = *(const f16x8*)(a1h + kt);
      }
    }
    GB_COMPUTE(0)
    // write pend step ksi+1 -> buf1 (always valid: ksi+1 <= 31)
    *(u32x4*)(Bs + 4096 + off0/2) = pack8(B1x0, B1x1);
    *(u32x4*)(Bs + 4096 + off1/2) = pack8(B1y0, B1y1);
    if constexpr (AF32) {
      *(u32x4*)(As + 4096 + off0/2) = pack8(A1x0, A1x1);
      *(u32x4*)(As + 4096 + off1/2) = pack8(A1y0, A1y1);
    } else {
      *(f16x8*)(As + 4096 + off0/2) = H1a;
      *(f16x8*)(As + 4096 + off1/2) = H1b;
    }
    __syncthreads();

    // ===== ODD: compute step ksi+1 from buf1 =====
    const bool ld1 = (ksi + 3 < 32);
    if (ld1) {
      const int kt = (ksi + 3) * 32;
      B1x0 = *(const float4*)(b0f + kt);  B1x1 = *(const float4*)(b0f + kt + 4);
      B1y0 = *(const float4*)(b1f + kt);  B1y1 = *(const float4*)(b1f + kt + 4);
      if constexpr (AF32) {
        A1x0 = *(const float4*)(a0f + kt);  A1x1 = *(const float4*)(a0f + kt + 4);
        A1y0 = *(const float4*)(a1f + kt);  A1y1 = *(const float4*)(a1f + kt + 4);
      } else {
        H1a = *(const f16x8*)(a0h + kt);    H1b = *(const f16x8*)(a1h + kt);
      }
    }
    GB_COMPUTE(4096)
    if (ld0) {   // write pend step ksi+2 -> buf0
      *(u32x4*)(Bs + off0/2) = pack8(B0x0, B0x1);
      *(u32x4*)(Bs + off1/2) = pack8(B0y0, B0y1);
      if constexpr (AF32) {
        *(u32x4*)(As + off0/2) = pack8(A0x0, A0x1);
        *(u32x4*)(As + off1/2) = pack8(A0y0, A0y1);
      } else {
        *(f16x8*)(As + off0/2) = H0a;
        *(f16x8*)(As + off1/2) = H0b;
      }
    }
    __syncthreads();
  }
  #undef GB_COMPUTE

  #pragma unroll
  for (int j = 0; j < 4; ++j) {
    const int col = n0 + wc*64 + j*16 + (l & 15);
    const float bb = bias[col];
    #pragma unroll
    for (int i = 0; i < 4; ++i) {
      const int rowb = m0 + wr*64 + i*16 + ((l>>4)<<2);
      #pragma unroll
      for (int r = 0; r < 4; ++r) {
        float v = acc[i][j][r] + bb;
        if constexpr (OUTF32) Cf[(size_t)(rowb+r)*N + col] = v;
        else                  Ch[(size_t)(rowb+r)*N + col] = (f16)v;
      }
    }
  }
}

// ---------------- batched QKV GEMM: grid (8,64,3), z selects {q,k,v} ----------------
__global__ __launch_bounds__(256)
void gemm_qkv(const float* __restrict__ q_in, const float* __restrict__ k_in,
              const float* __restrict__ v_in, const float* __restrict__ Wq,
              const float* __restrict__ Wk, const float* __restrict__ Wv,
              const float* __restrict__ bq, const float* __restrict__ bk,
              const float* __restrict__ bv, f16* __restrict__ Qp,
              f16* __restrict__ Kp, f16* __restrict__ Vp)
{
  __shared__ __align__(16) f16 As[2*128*32];
  __shared__ __align__(16) f16 Bs[2*128*32];
  const int z = blockIdx.z;
  const float* Asrc = (z == 0) ? q_in : (z == 1) ? k_in : v_in;
  const float* Bsrc = (z == 0) ? Wq : (z == 1) ? Wk : Wv;
  const float* bias = (z == 0) ? bq : (z == 1) ? bk : bv;
  f16* Ch = (z == 0) ? Qp : (z == 1) ? Kp : Vp;
  const int id = blockIdx.x + blockIdx.y * gridDim.x;
  gemm_body<true, false>(Asrc, Bsrc, bias, nullptr, Ch, id, As, Bs);
}

// ---------------- Wo GEMM: A f16 (attn out), B f32 weights, C f32 ----------------
__global__ __launch_bounds__(256)
void gemm_out(const f16* __restrict__ Op, const float* __restrict__ Wo,
              const float* __restrict__ bo, float* __restrict__ Out)
{
  __shared__ __align__(16) f16 As[2*128*32];
  __shared__ __align__(16) f16 Bs[2*128*32];
  const int id = blockIdx.x + blockIdx.y * gridDim.x;
  gemm_body<false, true>(Op, Wo, bo, Out, nullptr, id, As, Bs);
}

// ---------------- flash attention: R15/R20-proven (dbuf + tree-max + split psum + defer-rescale) ----------------
__global__ __launch_bounds__(256, 4)
void attn_kernel(const f16* __restrict__ Q, const f16* __restrict__ K,
                 const f16* __restrict__ V, f16* __restrict__ O)
{
  __shared__ __align__(16) f16 S_lds[16384];

  const int t = threadIdx.x, l = t & 63, w = t >> 6;
  const int lq = l & 31, hi = l >> 5;

  // XCD-bijective swizzle: all 16 q-tiles of one bh on one XCD
  const int lin = blockIdx.x + (blockIdx.y << 4);
  const int xcd = lin & 7, jj = lin >> 3;
  const int bh = xcd * 8 + (jj >> 4);
  const int qt = jj & 15;
  const int b = bh >> 4, h = bh & 15;
  const size_t base = (size_t)b * NS * NE + (size_t)h * ND;
  const int q = qt*128 + w*32 + lq;

  // Q B-fragments
  f16x8 bq[4];
  #pragma unroll
  for (int ks = 0; ks < 4; ++ks)
    bq[ks] = *(const f16x8*)&Q[base + (size_t)q*NE + ks*16 + hi*8];
  asm volatile("s_waitcnt vmcnt(0)" ::: "memory");

  f32x16 o[2];
  #pragma unroll
  for (int dt = 0; dt < 2; ++dt)
    #pragma unroll
    for (int r = 0; r < 16; ++r) o[dt][r] = 0.f;
  float m2 = -3e38f, lsum = 0.f;
  const float K2 = 0.125f * 1.44269504089f;

  // ---- K staging src (inverse-permuted; proven) ----
  const int krow0 = w*16 + (l>>3);
  const int kgran = ((l&7) ^ (l>>3)) * 8;
  const f16* kSrc0 = K + base + (size_t)krow0*NE + kgran;
  const f16* kSrc1 = kSrc0 + (size_t)8*NE;
  // ---- V staging src: lane = key row l, d-chunk = w*16..w*16+15 (proven) ----
  const f16* vSrc = V + base + (size_t)l*NE + w*16;

  const size_t tileAdv = (size_t)64 * NE;
  const int kd0 = (w*2+0)*512 + l*8;
  const int kd1 = (w*2+1)*512 + l*8;

  // ================= prologue: stage tile 0 into buf 0 =================
  f16x8 va, vb;
  {
    gld16(kSrc0, &S_lds[0] + kd0);
    gld16(kSrc1, &S_lds[0] + kd1);
    va = *(const f16x8*)(vSrc);
    vb = *(const f16x8*)(vSrc + 8);
    asm volatile("s_waitcnt vmcnt(0)" ::: "memory");
    char* vt0 = (char*)&S_lds[4096];
    #pragma unroll
    for (int i = 0; i < 8; ++i) {
      const int d0 = w*16 + i, d1 = w*16 + 8 + i;   // d&7 == i&7 for both
      *(f16*)(vt0 + ((d0*128 + l*2) ^ ((i & 7) << 4))) = va[i];
      *(f16*)(vt0 + ((d1*128 + l*2) ^ ((i & 7) << 4))) = vb[i];
    }
  }
  __syncthreads();

  for (int it = 0; it < 32; ++it) {
    const int cur = it & 1, nb = cur ^ 1;
    const char* ksb = (const char*)(&S_lds[cur*8192]);
    const char* vtb = (const char*)(&S_lds[cur*8192 + 4096]);

    // ---- issue next-tile staging loads (overlap with this tile's compute) ----
    if (it < 31) {
      const size_t g = (size_t)(it+1) * tileAdv;
      gld16(kSrc0 + g, &S_lds[nb*8192] + kd0);
      gld16(kSrc1 + g, &S_lds[nb*8192] + kd1);
      va = *(const f16x8*)(vSrc + g);
      vb = *(const f16x8*)(vSrc + g + 8);
    }

    // ---- S^T = K * Q^T ----
    f32x16 s[2];
    #pragma unroll
    for (int ct = 0; ct < 2; ++ct)
      #pragma unroll
      for (int r = 0; r < 16; ++r) s[ct][r] = 0.f;
    __builtin_amdgcn_s_setprio(1);
    #pragma unroll
    for (int ct = 0; ct < 2; ++ct) {
      const int krow = ct*32 + lq;
      const int rswz = (krow & 7) << 4;
      #pragma unroll
      for (int ks = 0; ks < 4; ++ks) {
        f16x8 ak = *(const f16x8*)(ksb + ((krow*128 + ks*32 + hi*16) ^ rswz));
        s[ct] = __builtin_amdgcn_mfma_f32_32x32x16_f16(ak, bq[ks], s[ct], 0, 0, 0);
      }
    }
    __builtin_amdgcn_s_setprio(0);

    // ---- pairwise-tree max (depth 5; exact reassociation) ----
    float mm[16];
    #pragma unroll
    for (int r = 0; r < 16; ++r) mm[r] = fmaxf(s[0][r], s[1][r]);
    #pragma unroll
    for (int st = 8; st > 0; st >>= 1)
      #pragma unroll
      for (int r = 0; r < st; ++r) mm[r] = fmaxf(mm[r], mm[r+st]);
    float mx = mm[0] * K2;
    mx = fmaxf(mx, __shfl_xor(mx, 32));

    // ---- defer-rescale (T13, THR=8 in log2) ----
    if (__any(mx > m2 + 8.0f)) {
      const float mnew = fmaxf(m2, mx);
      const float alpha = __builtin_amdgcn_exp2f(m2 - mnew);
      m2 = mnew;
      lsum *= alpha;
      #pragma unroll
      for (int dt = 0; dt < 2; ++dt)
        #pragma unroll
        for (int r = 0; r < 16; ++r) o[dt][r] *= alpha;
    }

    // ---- exp + 4-way split psum ----
    float ps4[4] = {0.f, 0.f, 0.f, 0.f};
    #pragma unroll
    for (int ct = 0; ct < 2; ++ct)
      #pragma unroll
      for (int r = 0; r < 16; ++r) {
        float p = __builtin_amdgcn_exp2f(s[ct][r]*K2 - m2);
        s[ct][r] = p;
        ps4[r & 3] += p;
      }
    lsum += (ps4[0] + ps4[1]) + (ps4[2] + ps4[3]);

    // ---- pack P, build PV B-operands via plswap (distinct values: proven) ----
    f16x8 pa[4];
    #pragma unroll
    for (int ct = 0; ct < 2; ++ct) {
      unsigned wd[8];
      #pragma unroll
      for (int m = 0; m < 4; ++m)
        #pragma unroll
        for (int hh = 0; hh < 2; ++hh)
          wd[m*2 + hh] = cvt2h(s[ct][4*m + 2*hh], s[ct][4*m + 2*hh + 1]);
      #pragma unroll
      for (int ks2 = 0; ks2 < 2; ++ks2) {
        unsigned a0 = wd[(2*ks2)*2 + 0], b0 = wd[(2*ks2+1)*2 + 0];
        unsigned a1 = wd[(2*ks2)*2 + 1], b1 = wd[(2*ks2+1)*2 + 1];
        plswap(a0, b0);
        plswap(a1, b1);
        union { unsigned u[4]; f16x8 v; } pp;
        pp.u[0] = a0; pp.u[1] = a1; pp.u[2] = b0; pp.u[3] = b1;
        pa[ct*2 + ks2] = pp.v;
      }
    }

    // ---- O^T += V^T * P ----
    __builtin_amdgcn_s_setprio(1);
    #pragma unroll
    for (int ks = 0; ks < 4; ++ks)
      #pragma unroll
      for (int dt = 0; dt < 2; ++dt) {
        const int drow = dt*32 + lq;
        f16x8 av = *(const f16x8*)(vtb + ((drow*128 + ks*32 + hi*16) ^ ((drow & 7) << 4)));
        o[dt] = __builtin_amdgcn_mfma_f32_32x32x16_f16(av, pa[ks], o[dt], 0, 0, 0);
      }
    __builtin_amdgcn_s_setprio(0);

    // ---- finish staging next tile: drain loads, write Vt, single barrier ----
    if (it < 31) {
      asm volatile("s_waitcnt vmcnt(0)" ::: "memory");
      char* vtn = (char*)(&S_lds[nb*8192 + 4096]);
      #pragma unroll
      for (int i = 0; i < 8; ++i) {
        const int d0 = w*16 + i, d1 = w*16 + 8 + i;
        *(f16*)(vtn + ((d0*128 + l*2) ^ ((i & 7) << 4))) = va[i];
        *(f16*)(vtn + ((d1*128 + l*2) ^ ((i & 7) << 4))) = vb[i];
      }
      __syncthreads();
    }
  }

  // ---- epilogue: cross-half lsum combine (shfl, proven), normalize, store ----
  const float lt = lsum + __shfl_xor(lsum, 32);
  const float linv = 1.0f / lt;
  #pragma unroll
  for (int dt = 0; dt < 2; ++dt)
    #pragma unroll
    for (int m = 0; m < 4; ++m) {
      u32x2 st;
      st.x = cvt2h(o[dt][4*m+0]*linv, o[dt][4*m+1]*linv);
      st.y = cvt2h(o[dt][4*m+2]*linv, o[dt][4*m+3]*linv);
      const int d = dt*32 + 8*m + 4*hi;
      *(u32x2*)&O[base + (size_t)q*NE + d] = st;
    }
}

// ---------------- launch ----------------
extern "C" void kernel_launch(void* const* d_in, const int* in_sizes, int n_in,
                              void* d_out, int out_size, void* d_ws, size_t ws_size,
                              hipStream_t stream)
{
  const float* q_in = (const float*)d_in[0];
  const float* k_in = (const float*)d_in[1];
  const float* v_in = (const float*)d_in[2];
  const float* Wq = (const float*)d_in[3];
  const float* bq = (const float*)d_in[4];
  const float* Wk = (const float*)d_in[5];
  const float* bk = (const float*)d_in[6];
  const float* Wv = (const float*)d_in[7];
  const float* bv = (const float*)d_in[8];
  const float* Wo = (const float*)d_in[9];
  const float* bo = (const float*)d_in[10];

  char* ws = (char*)d_ws;
  f16* Qp   = (f16*)(ws + 58720256);
  f16* Kp   = (f16*)(ws + 75497472);
  f16* Vp   = (f16*)(ws + 92274688);
  f16* Op   = (f16*)(ws + 109051904);

  gemm_qkv<<<dim3(8, 64, 3), 256, 0, stream>>>(q_in, k_in, v_in, Wq, Wk, Wv,
                                               bq, bk, bv, Qp, Kp, Vp);

  attn_kernel<<<dim3(16, 64), 256, 0, stream>>>(Qp, Kp, Vp, Op);

  gemm_out<<<dim3(8, 64), 256, 0, stream>>>(Op, Wo, bo, (float*)d_out);
}